// Round 12
// baseline (191.195 us; speedup 1.0000x reference)
//
#include <hip/hip_runtime.h>

typedef unsigned short u16;
typedef u16 u16x4 __attribute__((ext_vector_type(4)));
typedef u16 u16x8 __attribute__((ext_vector_type(8)));
typedef __bf16 bf16x8 __attribute__((ext_vector_type(8)));
typedef float floatx4 __attribute__((ext_vector_type(4)));

#define N_EMBD 1024
#define N_HEAD 16
#define HEAD_DIM 64
#define SEQ 2048
#define BATCH 2
#define M_ROWS (BATCH * SEQ)  // 4096

typedef __attribute__((address_space(1))) const unsigned char ga_t;
typedef __attribute__((address_space(3))) unsigned char la_t;

#if __has_builtin(__builtin_amdgcn_exp2f)
#define EXP2(x) __builtin_amdgcn_exp2f(x)
#else
#define EXP2(x) exp2f(x)
#endif

// native gfx950 f32->bf16 (RNE), 1 instr
__device__ __forceinline__ u16 cvt_bf16(float f) {
  return __builtin_bit_cast(u16, (__bf16)f);
}

// ======== prep: convert x (blocks 0..2047) + transpose both weights ========
__global__ __launch_bounds__(256) void prep(const float* __restrict__ x,
                                            u16* __restrict__ xb,
                                            const float* __restrict__ wa,
                                            const float* __restrict__ wp,
                                            u16* __restrict__ outa,
                                            u16* __restrict__ outp) {
  const int bid = blockIdx.x;
  if (bid < 2048) {  // convert_x
    const long i = ((long)bid * 256 + threadIdx.x) * 8;
    const float4 f0 = *(const float4*)&x[i];
    const float4 f1 = *(const float4*)&x[i + 4];
    u16x8 p;
    p[0] = cvt_bf16(f0.x); p[1] = cvt_bf16(f0.y);
    p[2] = cvt_bf16(f0.z); p[3] = cvt_bf16(f0.w);
    p[4] = cvt_bf16(f1.x); p[5] = cvt_bf16(f1.y);
    p[6] = cvt_bf16(f1.z); p[7] = cvt_bf16(f1.w);
    *(u16x8*)&xb[i] = p;
    return;
  }
  __shared__ u16 tile[32][33];
  const int t = bid - 2048;
  const int gx = t & 127;
  const int gy = t >> 7;
  const int R = N_EMBD;
  const float* in;
  u16* out;
  int C, bx;
  if (gx < 96) {
    in = wa; out = outa; C = 3 * N_EMBD; bx = gx * 32;
  } else {
    in = wp; out = outp; C = N_EMBD; bx = (gx - 96) * 32;
  }
  const int by = gy * 32;
  const int tx = threadIdx.x & 31;
  const int ty = threadIdx.x >> 5;
#pragma unroll
  for (int j = 0; j < 32; j += 8)
    tile[ty + j][tx] = cvt_bf16(in[(long)(by + ty + j) * C + bx + tx]);
  __syncthreads();
#pragma unroll
  for (int j = 0; j < 32; j += 8)
    out[(long)(bx + ty + j) * R + by + tx] = tile[tx][ty + j];
}

// ======== 128x128 GEMM, m97-style global_load_lds staging ========
// MODE 0: A=xb [M,K]; epilogue scatters q/k (bf16 [B,H,T,D]) and vT [B,H,D,T].
// MODE 1: A=q-buffer remap; epilogue writes fp32 out + bias.
#define BK 32

template <int MODE>
__global__ __launch_bounds__(256) void gemm128(
    const u16* __restrict__ A, const u16* __restrict__ Bt,
    const float* __restrict__ bias, float* __restrict__ out,
    u16* __restrict__ qo, u16* __restrict__ ko, u16* __restrict__ vo, int N,
    int K) {
  __shared__ u16 As[128 * BK];
  __shared__ u16 Bs[128 * BK];
  const int tid = threadIdx.x;
  const int bm = blockIdx.y * 128;
  const int bn = blockIdx.x * 128;
  const int w = tid >> 6;
  const int l = tid & 63;
  const int wm = (w >> 1) * 64;
  const int wn = (w & 1) * 64;
  const int m16 = l & 15;
  const int quad = l >> 4;
  const int lrow = l >> 2;
  const int lcol = (l & 3) * 8;

  floatx4 acc[4][4];
#pragma unroll
  for (int i = 0; i < 4; ++i)
#pragma unroll
    for (int j = 0; j < 4; ++j) acc[i][j] = (floatx4){0.f, 0.f, 0.f, 0.f};

  for (int kt = 0; kt < K; kt += BK) {
#pragma unroll
    for (int p = 0; p < 2; ++p) {
      const int arow = p * 64 + w * 16;
      long gA;
      if (MODE == 0) {
        gA = (long)(bm + arow + lrow) * K + kt + lcol;
      } else {
        const int m = bm + arow + lrow;
        const int b = m >> 11, t = m & 2047;
        const int k0 = kt + lcol;
        const int head = k0 >> 6, dd = k0 & 63;
        gA = (((long)(b * N_HEAD + head)) * SEQ + t) * HEAD_DIM + dd;
      }
      __builtin_amdgcn_global_load_lds((ga_t*)(A + gA), (la_t*)&As[arow * BK],
                                       16, 0, 0);
      const long gB = (long)(bn + arow + lrow) * K + kt + lcol;
      __builtin_amdgcn_global_load_lds((ga_t*)(Bt + gB), (la_t*)&Bs[arow * BK],
                                       16, 0, 0);
    }
    __syncthreads();

    bf16x8 af[4], bfr[4];
#pragma unroll
    for (int i = 0; i < 4; ++i)
      af[i] = __builtin_bit_cast(
          bf16x8, *(const u16x8*)&As[(wm + i * 16 + m16) * BK + quad * 8]);
#pragma unroll
    for (int j = 0; j < 4; ++j)
      bfr[j] = __builtin_bit_cast(
          bf16x8, *(const u16x8*)&Bs[(wn + j * 16 + m16) * BK + quad * 8]);
#pragma unroll
    for (int i = 0; i < 4; ++i)
#pragma unroll
      for (int j = 0; j < 4; ++j)
        acc[i][j] = __builtin_amdgcn_mfma_f32_16x16x32_bf16(af[i], bfr[j],
                                                            acc[i][j], 0, 0, 0);
    __syncthreads();
  }

#pragma unroll
  for (int i = 0; i < 4; ++i) {
#pragma unroll
    for (int j = 0; j < 4; ++j) {
      const int col = bn + wn + j * 16 + m16;
      const float bv = bias[col];
      if (MODE == 1) {
#pragma unroll
        for (int r = 0; r < 4; ++r) {
          const int row = bm + wm + i * 16 + quad * 4 + r;
          out[(long)row * N_EMBD + col] = acc[i][j][r] + bv;
        }
      } else {
        const int which = col >> 10;  // 0=q 1=k 2=v (wave-uniform)
        const int cc = col & 1023;
        const int h = cc >> 6;
        const int dd = cc & 63;
        const int row0 = bm + wm + i * 16 + quad * 4;
        const int b = row0 >> 11;
        const int t0 = row0 & 2047;
        if (which == 2) {
          u16x4 pk;
#pragma unroll
          for (int r = 0; r < 4; ++r) pk[r] = cvt_bf16(acc[i][j][r] + bv);
          *(u16x4*)&vo[(((long)(b * N_HEAD + h)) * HEAD_DIM + dd) * SEQ + t0] =
              pk;
        } else {
          u16* dst = (which == 0) ? qo : ko;
#pragma unroll
          for (int r = 0; r < 4; ++r)
            dst[(((long)(b * N_HEAD + h)) * SEQ + t0 + r) * HEAD_DIM + dd] =
                cvt_bf16(acc[i][j][r] + bv);
        }
      }
    }
  }
}

// ======== flash attention — S^T, single-buffer LDS (27.6KB, 5 blk/CU) =====
// 1024 blocks, one q-tile each, heavy-first + XCD-affine id.
// Register prefetch spans the compute phase; 2 barriers/iter.
#define BQ 64
#define BKV 64
#define KPAD 72
#define LOG2E 1.44269504f
#define NQT (SEQ / BQ)  // 32 q-tiles

__device__ __forceinline__ void load_kv(const u16* __restrict__ K,
                                        const u16* __restrict__ Vt, long bh,
                                        int kt, int tid, u16x8 kreg[2],
                                        u16x8 vreg[2]) {
#pragma unroll
  for (int i = 0; i < 2; ++i) {
    const int p = tid + 256 * i;
    const int kkey = p >> 3, kdg = p & 7;
    kreg[i] = *(const u16x8*)&K[(bh * SEQ + kt + kkey) * HEAD_DIM + kdg * 8];
    const int vd = p >> 3, vkg = (p & 7) * 8;  // Vt row d, 8 keys
    vreg[i] = *(const u16x8*)&Vt[(bh * HEAD_DIM + vd) * SEQ + kt + vkg];
  }
}

__global__ __launch_bounds__(256) void flash_attn(u16* __restrict__ Qy,
                                                  const u16* __restrict__ K,
                                                  const u16* __restrict__ Vt) {
  const int id = blockIdx.x;
  const int iq = (NQT - 1) - (id >> 5);
  const int bh_ = ((id >> 3) & 3) * 8 + (id & 7);
  const long bh = bh_;
  const int tid = threadIdx.x;
  const int w = tid >> 6;
  const int l = tid & 63;
  const int m16 = l & 15;
  const int quad = l >> 4;

  __shared__ u16 Kl[BKV * KPAD];       // [key][d]   9.2 KB
  __shared__ u16 Vl[HEAD_DIM * KPAD];  // [d][key]   9.2 KB
  __shared__ u16 Pl[4][16 * KPAD];     // per-wave [q][key] 9.2 KB

  const float SC = 0.125f * LOG2E;

  const int qb = iq * BQ;
  const int ntiles = iq + 1;
  const int qglob = qb + w * 16 + m16;

  bf16x8 qf[2];
  {
    const u16* qrow = Qy + (bh * SEQ + qglob) * HEAD_DIM;
    qf[0] = __builtin_bit_cast(bf16x8, *(const u16x8*)&qrow[quad * 8]);
    qf[1] = __builtin_bit_cast(bf16x8, *(const u16x8*)&qrow[32 + quad * 8]);
  }

  floatx4 Oacc[4];  // O^T: col=q=m16, row=d = t*16 + quad*4 + r
#pragma unroll
  for (int t = 0; t < 4; ++t) Oacc[t] = (floatx4){0.f, 0.f, 0.f, 0.f};
  float mrow = -1e30f, lrow = 0.f;

  u16x8 kreg[2], vreg[2];
  load_kv(K, Vt, bh, 0, tid, kreg, vreg);

  for (int it = 0; it < ntiles; ++it) {
    // ---- write prefetched regs -> single LDS buffers ----
#pragma unroll
    for (int i = 0; i < 2; ++i) {
      const int p = tid + 256 * i;
      const int kkey = p >> 3, kdg = p & 7;
      *(u16x8*)&Kl[kkey * KPAD + kdg * 8] = kreg[i];
      const int vd = p >> 3, vkg = (p & 7) * 8;
      *(u16x8*)&Vl[vd * KPAD + vkg] = vreg[i];
    }
    __syncthreads();  // barrier A: staging visible to all
    if (it + 1 < ntiles) load_kv(K, Vt, bh, (it + 1) * BKV, tid, kreg, vreg);

    // ---- S^T = K Q^T (raw scores; scale folded into exp FMA) ----
    floatx4 s[4];
#pragma unroll
    for (int j = 0; j < 4; ++j) s[j] = (floatx4){0.f, 0.f, 0.f, 0.f};
#pragma unroll
    for (int j = 0; j < 4; ++j)
#pragma unroll
      for (int kk = 0; kk < 2; ++kk) {
        const bf16x8 kf = __builtin_bit_cast(
            bf16x8,
            *(const u16x8*)&Kl[(j * 16 + m16) * KPAD + kk * 32 + quad * 8]);
        s[j] = __builtin_amdgcn_mfma_f32_16x16x32_bf16(kf, qf[kk], s[j], 0, 0,
                                                       0);
      }
    if (it == ntiles - 1) {
      const int kt = it * BKV;
#pragma unroll
      for (int j = 0; j < 4; ++j) {
        const int key0 = kt + j * 16 + quad * 4;
#pragma unroll
        for (int r = 0; r < 4; ++r)
          if (key0 + r > qglob) s[j][r] = -1e30f;
      }
    }

    // ---- online softmax ----
    float tm = s[0][0];
#pragma unroll
    for (int j = 0; j < 4; ++j)
#pragma unroll
      for (int r = 0; r < 4; ++r) tm = fmaxf(tm, s[j][r]);
    tm = fmaxf(tm, __shfl_xor(tm, 16, 64));
    tm = fmaxf(tm, __shfl_xor(tm, 32, 64));
    const float mn = fmaxf(mrow, tm * SC);
    const float al = EXP2(mrow - mn);
    mrow = mn;

    float ls = 0.f;
#pragma unroll
    for (int j = 0; j < 4; ++j) {
      u16x4 pk;
#pragma unroll
      for (int r = 0; r < 4; ++r) {
        const float p = EXP2(__builtin_fmaf(s[j][r], SC, -mn));
        ls += p;
        pk[r] = cvt_bf16(p);
      }
      *(u16x4*)&Pl[w][m16 * KPAD + j * 16 + quad * 4] = pk;
    }
    ls += __shfl_xor(ls, 16, 64);
    ls += __shfl_xor(ls, 32, 64);
    lrow = lrow * al + ls;
#pragma unroll
    for (int t = 0; t < 4; ++t)
#pragma unroll
      for (int r = 0; r < 4; ++r) Oacc[t][r] *= al;

    // ---- O^T += V^T P^T ----
    bf16x8 pf[2];
    pf[0] = __builtin_bit_cast(bf16x8,
                               *(const u16x8*)&Pl[w][m16 * KPAD + quad * 8]);
    pf[1] = __builtin_bit_cast(
        bf16x8, *(const u16x8*)&Pl[w][m16 * KPAD + 32 + quad * 8]);
#pragma unroll
    for (int t = 0; t < 4; ++t)
#pragma unroll
      for (int kk = 0; kk < 2; ++kk) {
        const bf16x8 vf = __builtin_bit_cast(
            bf16x8,
            *(const u16x8*)&Vl[(t * 16 + m16) * KPAD + kk * 32 + quad * 8]);
        Oacc[t] = __builtin_amdgcn_mfma_f32_16x16x32_bf16(vf, pf[kk], Oacc[t],
                                                          0, 0, 0);
      }
    __syncthreads();  // barrier B: PV done before next staging write
  }

  // ---- epilogue: O^T lane holds (d = t*16+quad*4+r, q = m16) ----
  const float invl = 1.f / lrow;
#pragma unroll
  for (int t = 0; t < 4; ++t) {
    u16x4 pk;
#pragma unroll
    for (int r = 0; r < 4; ++r) pk[r] = cvt_bf16(Oacc[t][r] * invl);
    *(u16x4*)&Qy[(bh * SEQ + qglob) * HEAD_DIM + t * 16 + quad * 4] = pk;
  }
}

// ======== launch ========
extern "C" void kernel_launch(void* const* d_in, const int* in_sizes, int n_in,
                              void* d_out, int out_size, void* d_ws,
                              size_t ws_size, hipStream_t stream) {
  const float* x = (const float*)d_in[0];
  const float* w_attn = (const float*)d_in[1];
  const float* b_attn = (const float*)d_in[2];
  const float* w_proj = (const float*)d_in[3];
  const float* b_proj = (const float*)d_in[4];
  float* out = (float*)d_out;

  // ws: q 8 | k 8 | vT 8 | wT_a 6 | wT_p 2 | xb 8  = 40 MB
  char* ws = (char*)d_ws;
  const size_t SZ = (size_t)BATCH * N_HEAD * SEQ * HEAD_DIM * sizeof(u16);
  u16* q = (u16*)(ws);
  u16* k = (u16*)(ws + SZ);
  u16* vT = (u16*)(ws + 2 * SZ);
  u16* wT_a = (u16*)(ws + 3 * SZ);
  u16* wT_p = (u16*)(ws + 3 * SZ + (size_t)3 * N_EMBD * N_EMBD * sizeof(u16));
  u16* xb = (u16*)(ws + 3 * SZ + (size_t)4 * N_EMBD * N_EMBD * sizeof(u16));

  prep<<<2048 + 4096, 256, 0, stream>>>(x, xb, w_attn, w_proj, wT_a, wT_p);

  gemm128<0><<<dim3(3 * N_EMBD / 128, M_ROWS / 128), 256, 0, stream>>>(
      xb, wT_a, b_attn, nullptr, q, k, vT, 3 * N_EMBD, N_EMBD);

  flash_attn<<<NQT * 32, 256, 0, stream>>>(q, k, vT);

  gemm128<1><<<dim3(N_EMBD / 128, M_ROWS / 128), 256, 0, stream>>>(
      q, wT_p, b_proj, out, nullptr, nullptr, nullptr, N_EMBD, N_EMBD);
}